// Round 1
// baseline (5731.893 us; speedup 1.0000x reference)
//
#include <hip/hip_runtime.h>
#include <math.h>

// ---- constants -------------------------------------------------------------
#define BB 2
#define SS 4096
#define DD 768
#define HH 12
#define DH 64
#define LL 12
#define DFF 3072
#define NC 16
#define WW 32
#define CC (SS/WW)          // 128
#define MM (BB*SS)          // 8192

typedef __bf16 bf16x8 __attribute__((ext_vector_type(8)));
typedef __bf16 bf16x4 __attribute__((ext_vector_type(4)));
typedef float  f32x4  __attribute__((ext_vector_type(4)));

// ---- weight transpose + bf16 convert: dst[n][k] = bf16(src[k][n]*scale) ----
__global__ __launch_bounds__(256) void transpose_w(const float* __restrict__ src,
                                                   __bf16* __restrict__ dst,
                                                   int K, int N, float scale)
{
    __shared__ float t[32][33];
    int nt = blockIdx.x, kt = blockIdx.y;
    int tx = threadIdx.x & 31, ty = threadIdx.x >> 5;   // 32 x 8
    int n0 = nt * 32, k0 = kt * 32;
    #pragma unroll
    for (int j = 0; j < 4; j++) {
        int k = k0 + ty + j * 8;
        t[ty + j * 8][tx] = src[(size_t)k * N + n0 + tx];
    }
    __syncthreads();
    #pragma unroll
    for (int j = 0; j < 4; j++) {
        int n = n0 + ty + j * 8;
        dst[(size_t)n * K + k0 + tx] = (__bf16)(t[tx][ty + j * 8] * scale);
    }
}

__global__ void prep_bias_qkv(const float* __restrict__ bq, const float* __restrict__ bk,
                              const float* __restrict__ bv, float* __restrict__ outb)
{
    int i = blockIdx.x * 256 + threadIdx.x;   // 0..2303
    if (i >= 3 * DD) return;
    if (i < DD)            outb[i] = bq[i] * 0.125f;
    else if (i < 2 * DD)   outb[i] = bk[i - DD];
    else                   outb[i] = bv[i - 2 * DD];
}

// ---- GEMM: C[M,N] = act(A[M,K] @ Bt[N,K]^T + bias) ------------------------
// A, Bt bf16 (k-major both). 128x128 tile, 4 waves, 16x16x32 MFMA.
#define LDT 40
template<int ACT, int OUTBF>
__global__ __launch_bounds__(256) void gemm_bt(const __bf16* __restrict__ A,
                                               const __bf16* __restrict__ Bt,
                                               const float* __restrict__ bias,
                                               void* __restrict__ Cout,
                                               int M, int N, int K)
{
    __shared__ __bf16 As[128 * LDT];
    __shared__ __bf16 Bs[128 * LDT];
    const int tid  = threadIdx.x;
    const int lane = tid & 63, w = tid >> 6;
    const int wrow = w >> 1, wcol = w & 1;
    const int quad = lane >> 4, lr = lane & 15;
    const size_t m0 = (size_t)blockIdx.y * 128, n0 = (size_t)blockIdx.x * 128;

    f32x4 acc[4][4] = {};

    const int r0 = tid >> 2, sg = tid & 3;        // chunk 0: rows 0..63
    const int r1 = r0 + 64;                       // chunk 1: rows 64..127
    const __bf16* Abase = A  + m0 * K;
    const __bf16* Bbase = Bt + n0 * K;

    for (int k0 = 0; k0 < K; k0 += 32) {
        __syncthreads();
        uint4 va0 = *(const uint4*)(Abase + (size_t)r0 * K + k0 + sg * 8);
        uint4 va1 = *(const uint4*)(Abase + (size_t)r1 * K + k0 + sg * 8);
        uint4 vb0 = *(const uint4*)(Bbase + (size_t)r0 * K + k0 + sg * 8);
        uint4 vb1 = *(const uint4*)(Bbase + (size_t)r1 * K + k0 + sg * 8);
        *(uint4*)&As[r0 * LDT + sg * 8] = va0;
        *(uint4*)&As[r1 * LDT + sg * 8] = va1;
        *(uint4*)&Bs[r0 * LDT + sg * 8] = vb0;
        *(uint4*)&Bs[r1 * LDT + sg * 8] = vb1;
        __syncthreads();

        bf16x8 af[4], bfv[4];
        #pragma unroll
        for (int mt = 0; mt < 4; mt++)
            af[mt] = *(const bf16x8*)&As[(wrow * 64 + mt * 16 + lr) * LDT + quad * 8];
        #pragma unroll
        for (int nt = 0; nt < 4; nt++)
            bfv[nt] = *(const bf16x8*)&Bs[(wcol * 64 + nt * 16 + lr) * LDT + quad * 8];
        #pragma unroll
        for (int mt = 0; mt < 4; mt++)
            #pragma unroll
            for (int nt = 0; nt < 4; nt++)
                acc[mt][nt] = __builtin_amdgcn_mfma_f32_16x16x32_bf16(af[mt], bfv[nt], acc[mt][nt], 0, 0, 0);
    }

    #pragma unroll
    for (int nt = 0; nt < 4; nt++) {
        size_t col = n0 + wcol * 64 + nt * 16 + lr;
        float bvv = bias[col];
        #pragma unroll
        for (int mt = 0; mt < 4; mt++) {
            int rowb = wrow * 64 + mt * 16 + quad * 4;
            #pragma unroll
            for (int r = 0; r < 4; r++) {
                float v = acc[mt][nt][r] + bvv;
                if (ACT == 1) v = 0.5f * v * (1.0f + erff(v * 0.70710678118654752f));
                size_t off = (m0 + rowb + r) * (size_t)N + col;
                if (OUTBF) ((__bf16*)Cout)[off] = (__bf16)v;
                else       ((float*)Cout)[off]  = v;
            }
        }
    }
}

// ---- band attention: qkv bf16 [M, 3*D] (H-major heads) -> attn bf16 [M, D] -
__global__ __launch_bounds__(256) void band_attn(const __bf16* __restrict__ qkv,
                                                 __bf16* __restrict__ attn)
{
    __shared__ float Qs[32][68];
    __shared__ float Ks[96][68];
    __shared__ float Vs[96][68];
    __shared__ float Ps[4][96];
    const int tid = threadIdx.x;
    const int c  = blockIdx.x & (CC - 1);
    const int hh = (blockIdx.x >> 7) % HH;
    const int b  = blockIdx.x / (CC * HH);
    const int qoff = hh * DH, koff = DD + hh * DH, voff = 2 * DD + hh * DH;

    // load Q (32 x 64)
    #pragma unroll
    for (int j = 0; j < 2; j++) {
        int idx = tid + j * 256;             // 512 quads
        int i = idx >> 4, d = (idx & 15) * 4;
        size_t base = ((size_t)(b * SS + c * WW + i)) * (3 * DD);
        bf16x4 v = *(const bf16x4*)(qkv + base + qoff + d);
        Qs[i][d] = (float)v[0]; Qs[i][d + 1] = (float)v[1];
        Qs[i][d + 2] = (float)v[2]; Qs[i][d + 3] = (float)v[3];
    }
    // load K, V (96 x 64) with boundary zero-fill
    #pragma unroll
    for (int j = 0; j < 6; j++) {
        int idx = tid + j * 256;             // 1536 quads
        int g = idx >> 4, d = (idx & 15) * 4;
        int kp = c * WW - WW + g;
        float k0 = 0, k1 = 0, k2 = 0, k3 = 0, v0 = 0, v1 = 0, v2 = 0, v3 = 0;
        if (kp >= 0 && kp < SS) {
            size_t base = ((size_t)(b * SS + kp)) * (3 * DD);
            bf16x4 kv = *(const bf16x4*)(qkv + base + koff + d);
            bf16x4 vv = *(const bf16x4*)(qkv + base + voff + d);
            k0 = kv[0]; k1 = kv[1]; k2 = kv[2]; k3 = kv[3];
            v0 = vv[0]; v1 = vv[1]; v2 = vv[2]; v3 = vv[3];
        }
        Ks[g][d] = k0; Ks[g][d + 1] = k1; Ks[g][d + 2] = k2; Ks[g][d + 3] = k3;
        Vs[g][d] = v0; Vs[g][d + 1] = v1; Vs[g][d + 2] = v2; Vs[g][d + 3] = v3;
    }
    __syncthreads();

    const int w = tid >> 6, lane = tid & 63;
    const int l31 = lane & 31;
    for (int it = 0; it < 8; it++) {
        int i = w * 8 + it;                  // query row in chunk
        float s0 = 0.f, s1 = 0.f;
        int g2 = 64 + l31;
        #pragma unroll
        for (int d4 = 0; d4 < 16; d4++) {
            float4 q  = *(float4*)&Qs[i][d4 * 4];
            float4 ka = *(float4*)&Ks[lane][d4 * 4];
            float4 kb = *(float4*)&Ks[g2][d4 * 4];
            s0 += q.x * ka.x + q.y * ka.y + q.z * ka.z + q.w * ka.w;
            s1 += q.x * kb.x + q.y * kb.y + q.z * kb.z + q.w * kb.w;
        }
        int kp0 = c * WW - WW + lane;
        bool m0 = (lane >= i) && (kp0 >= 0);                               // g in [i, i+64], key>=0
        bool m1 = (lane < 32) && (l31 <= i) && (c * WW + WW + l31 < SS);   // upper band, key<S
        s0 = m0 ? s0 : -3.0e38f;
        s1 = m1 ? s1 : -3.0e38f;
        float mx = fmaxf(s0, s1);
        #pragma unroll
        for (int off = 32; off; off >>= 1) mx = fmaxf(mx, __shfl_xor(mx, off));
        float e0 = m0 ? __expf(s0 - mx) : 0.f;
        float e1 = m1 ? __expf(s1 - mx) : 0.f;
        float sm = e0 + e1;
        #pragma unroll
        for (int off = 32; off; off >>= 1) sm += __shfl_xor(sm, off);
        float inv = 1.f / sm;
        Ps[w][lane] = e0 * inv;
        if (lane < 32) Ps[w][64 + lane] = e1 * inv;
        // PV: lane -> (group gg of 24 keys, 4 output dims)
        int gg = lane >> 4, d4 = (lane & 15) * 4;
        float4 o = {0.f, 0.f, 0.f, 0.f};
        #pragma unroll
        for (int j = 0; j < 24; j++) {
            int g = gg * 24 + j;
            float p = Ps[w][g];
            float4 vv = *(float4*)&Vs[g][d4];
            o.x += p * vv.x; o.y += p * vv.y; o.z += p * vv.z; o.w += p * vv.w;
        }
        o.x += __shfl_xor(o.x, 16); o.y += __shfl_xor(o.y, 16);
        o.z += __shfl_xor(o.z, 16); o.w += __shfl_xor(o.w, 16);
        o.x += __shfl_xor(o.x, 32); o.y += __shfl_xor(o.y, 32);
        o.z += __shfl_xor(o.z, 32); o.w += __shfl_xor(o.w, 32);
        if (lane < 16) {
            bf16x4 ov;
            ov[0] = (__bf16)o.x; ov[1] = (__bf16)o.y; ov[2] = (__bf16)o.z; ov[3] = (__bf16)o.w;
            *(bf16x4*)(attn + ((size_t)(b * SS + c * WW + i)) * DD + hh * DH + d4) = ov;
        }
    }
}

// ---- fused residual + layernorm: h = LN(h + tmp); hb = bf16(h) ------------
__global__ __launch_bounds__(256) void res_ln(float* __restrict__ h, const float* __restrict__ tmp,
                                              const float* __restrict__ gam, const float* __restrict__ bet,
                                              __bf16* __restrict__ hb)
{
    const int row = blockIdx.x, tid = threadIdx.x;
    const size_t base = (size_t)row * DD;
    float x[3]; float s = 0.f, q = 0.f;
    #pragma unroll
    for (int j = 0; j < 3; j++) {
        int d = tid + j * 256;
        float v = h[base + d] + tmp[base + d];
        x[j] = v; s += v; q += v * v;
    }
    __shared__ float red[8];
    int lane = tid & 63, w = tid >> 6;
    #pragma unroll
    for (int off = 32; off; off >>= 1) { s += __shfl_xor(s, off); q += __shfl_xor(q, off); }
    if (lane == 0) { red[w] = s; red[4 + w] = q; }
    __syncthreads();
    float S = red[0] + red[1] + red[2] + red[3];
    float Q = red[4] + red[5] + red[6] + red[7];
    float mean = S * (1.f / DD);
    float var  = fmaxf(Q * (1.f / DD) - mean * mean, 0.f);
    float rinv = rsqrtf(var + 1e-12f);
    #pragma unroll
    for (int j = 0; j < 3; j++) {
        int d = tid + j * 256;
        float y = (x[j] - mean) * rinv * gam[d] + bet[d];
        h[base + d] = y; hb[base + d] = (__bf16)y;
    }
}

// ---- embedding + layernorm ------------------------------------------------
__global__ __launch_bounds__(256) void embed_ln(const int* __restrict__ ids, const float* __restrict__ emb,
                                                const float* __restrict__ pos, const float* __restrict__ tok,
                                                const float* __restrict__ gam, const float* __restrict__ bet,
                                                float* __restrict__ h, __bf16* __restrict__ hb)
{
    const int row = blockIdx.x, tid = threadIdx.x;
    const int srow = row & (SS - 1);
    const int id = ids[row];
    const size_t base = (size_t)row * DD;
    float x[3]; float s = 0.f, q = 0.f;
    #pragma unroll
    for (int j = 0; j < 3; j++) {
        int d = tid + j * 256;
        float v = emb[(size_t)id * DD + d] + pos[(size_t)(srow + 1) * DD + d] + tok[d];
        x[j] = v; s += v; q += v * v;
    }
    __shared__ float red[8];
    int lane = tid & 63, w = tid >> 6;
    #pragma unroll
    for (int off = 32; off; off >>= 1) { s += __shfl_xor(s, off); q += __shfl_xor(q, off); }
    if (lane == 0) { red[w] = s; red[4 + w] = q; }
    __syncthreads();
    float S = red[0] + red[1] + red[2] + red[3];
    float Q = red[4] + red[5] + red[6] + red[7];
    float mean = S * (1.f / DD);
    float var  = fmaxf(Q * (1.f / DD) - mean * mean, 0.f);
    float rinv = rsqrtf(var + 1e-12f);
    #pragma unroll
    for (int j = 0; j < 3; j++) {
        int d = tid + j * 256;
        float y = (x[j] - mean) * rinv * gam[d] + bet[d];
        h[base + d] = y; hb[base + d] = (__bf16)y;
    }
}

// ---- final mean over S + tiny FC ------------------------------------------
__global__ void zero_kernel(float* __restrict__ p, int n)
{
    int i = blockIdx.x * 256 + threadIdx.x;
    if (i < n) p[i] = 0.f;
}

__global__ __launch_bounds__(256) void mean_kernel(const float* __restrict__ h, float* __restrict__ meanb)
{
    // grid: B * 32 * 3
    int blk = blockIdx.x;
    int b = blk / 96, rem = blk % 96;
    int sc = rem / 3, dg = rem % 3;
    int d = dg * 256 + threadIdx.x;
    float acc = 0.f;
    size_t base = ((size_t)b * SS + sc * 128) * DD + d;
    for (int s = 0; s < 128; s++) acc += h[base + (size_t)s * DD];
    atomicAdd(&meanb[b * DD + d], acc * (1.f / SS));
}

__global__ void fc_kernel(const float* __restrict__ meanb, const float* __restrict__ fw,
                          const float* __restrict__ fb, float* __restrict__ out)
{
    int b = blockIdx.x >> 4, n = blockIdx.x & 15;
    int lane = threadIdx.x;
    float acc = 0.f;
    #pragma unroll
    for (int j = 0; j < 12; j++) {
        int d = lane + j * 64;
        acc += meanb[b * DD + d] * fw[(size_t)d * NC + n];
    }
    #pragma unroll
    for (int off = 32; off; off >>= 1) acc += __shfl_xor(acc, off);
    if (lane == 0) out[b * NC + n] = acc + fb[n];
}

// ---- host -----------------------------------------------------------------
extern "C" void kernel_launch(void* const* d_in, const int* in_sizes, int n_in,
                              void* d_out, int out_size, void* d_ws, size_t ws_size,
                              hipStream_t stream)
{
    const int*   x    = (const int*)d_in[0];
    const float* emb  = (const float*)d_in[1];
    const float* pos  = (const float*)d_in[2];
    const float* tok  = (const float*)d_in[3];
    const float* elns = (const float*)d_in[4];
    const float* elnb = (const float*)d_in[5];
    const float* Wq   = (const float*)d_in[6];
    const float* bq   = (const float*)d_in[7];
    const float* Wk   = (const float*)d_in[8];
    const float* bk   = (const float*)d_in[9];
    const float* Wv   = (const float*)d_in[10];
    const float* bv   = (const float*)d_in[11];
    const float* Wo   = (const float*)d_in[12];
    const float* bo   = (const float*)d_in[13];
    const float* ln1s = (const float*)d_in[14];
    const float* ln1b = (const float*)d_in[15];
    const float* W1   = (const float*)d_in[16];
    const float* b1   = (const float*)d_in[17];
    const float* W2   = (const float*)d_in[18];
    const float* b2   = (const float*)d_in[19];
    const float* ln2s = (const float*)d_in[20];
    const float* ln2b = (const float*)d_in[21];
    const float* fcw  = (const float*)d_in[22];
    const float* fcb  = (const float*)d_in[23];
    float* out = (float*)d_out;

    char* wsp = (char*)d_ws;
    size_t off = 0;
    auto take = [&](size_t bytes) -> char* {
        char* p = wsp + off;
        off += (bytes + 255) & ~(size_t)255;
        return p;
    };
    float*  h    = (float*) take((size_t)MM * DD * 4);
    float*  tmp  = (float*) take((size_t)MM * DD * 4);
    __bf16* hb   = (__bf16*)take((size_t)MM * DD * 2);
    __bf16* qkv  = (__bf16*)take((size_t)MM * DFF * 2);  // union: qkv [M,2304] / ffh [M,3072]
    __bf16* ffh  = qkv;
    __bf16* attn = (__bf16*)take((size_t)MM * DD * 2);
    __bf16* wbt  = (__bf16*)take((size_t)DD * DFF * 2);  // per-GEMM transposed weights
    float*  bqkv = (float*) take(3 * DD * 4);
    float*  mnb  = (float*) take(BB * DD * 4);
    (void)ws_size; (void)in_sizes; (void)n_in; (void)out_size;

    embed_ln<<<MM, 256, 0, stream>>>(x, emb, pos, tok, elns, elnb, h, hb);

    for (int l = 0; l < LL; l++) {
        const float* Wq_l = Wq + (size_t)l * DD * DD;
        const float* Wk_l = Wk + (size_t)l * DD * DD;
        const float* Wv_l = Wv + (size_t)l * DD * DD;
        const float* Wo_l = Wo + (size_t)l * DD * DD;
        const float* W1_l = W1 + (size_t)l * DD * DFF;
        const float* W2_l = W2 + (size_t)l * DFF * DD;

        // QKV projection (scale folded into Wq/bq)
        transpose_w<<<dim3(24, 24), 256, 0, stream>>>(Wq_l, wbt,                 DD, DD, 0.125f);
        transpose_w<<<dim3(24, 24), 256, 0, stream>>>(Wk_l, wbt + DD * DD,       DD, DD, 1.f);
        transpose_w<<<dim3(24, 24), 256, 0, stream>>>(Wv_l, wbt + 2 * DD * DD,   DD, DD, 1.f);
        prep_bias_qkv<<<9, 256, 0, stream>>>(bq + l * DD, bk + l * DD, bv + l * DD, bqkv);
        gemm_bt<0, 1><<<dim3(18, 64), 256, 0, stream>>>(hb, wbt, bqkv, qkv, MM, 3 * DD, DD);

        band_attn<<<BB * HH * CC, 256, 0, stream>>>(qkv, attn);

        // output projection + LN1
        transpose_w<<<dim3(24, 24), 256, 0, stream>>>(Wo_l, wbt, DD, DD, 1.f);
        gemm_bt<0, 0><<<dim3(6, 64), 256, 0, stream>>>(attn, wbt, bo + l * DD, tmp, MM, DD, DD);
        res_ln<<<MM, 256, 0, stream>>>(h, tmp, ln1s + l * DD, ln1b + l * DD, hb);

        // FFN
        transpose_w<<<dim3(96, 24), 256, 0, stream>>>(W1_l, wbt, DD, DFF, 1.f);
        gemm_bt<1, 1><<<dim3(24, 64), 256, 0, stream>>>(hb, wbt, b1 + l * DFF, ffh, MM, DFF, DD);
        transpose_w<<<dim3(24, 96), 256, 0, stream>>>(W2_l, wbt, DFF, DD, 1.f);
        gemm_bt<0, 0><<<dim3(6, 64), 256, 0, stream>>>(ffh, wbt, b2 + l * DD, tmp, MM, DD, DFF);
        res_ln<<<MM, 256, 0, stream>>>(h, tmp, ln2s + l * DD, ln2b + l * DD, hb);
    }

    zero_kernel<<<6, 256, 0, stream>>>(mnb, BB * DD);
    mean_kernel<<<BB * 32 * 3, 256, 0, stream>>>(h, mnb);
    fc_kernel<<<BB * NC, 64, 0, stream>>>(mnb, fcw, fcb, out);
}

// Round 2
// 3997.293 us; speedup vs baseline: 1.4339x; 1.4339x over previous
//
#include <hip/hip_runtime.h>
#include <math.h>

// ---- constants -------------------------------------------------------------
#define BB 2
#define SS 4096
#define DD 768
#define HH 12
#define DH 64
#define LL 12
#define DFF 3072
#define NC 16
#define WW 32
#define CC (SS/WW)          // 128
#define MM (BB*SS)          // 8192

typedef __bf16 bf16x8 __attribute__((ext_vector_type(8)));
typedef __bf16 bf16x4 __attribute__((ext_vector_type(4)));
typedef float  f32x4  __attribute__((ext_vector_type(4)));

// ---- weight transpose + bf16 convert: dst[n][k] = bf16(src[k][n]*scale) ----
__global__ __launch_bounds__(256) void transpose_w(const float* __restrict__ src,
                                                   __bf16* __restrict__ dst,
                                                   int K, int N, float scale)
{
    __shared__ float t[32][33];
    int nt = blockIdx.x, kt = blockIdx.y;
    int tx = threadIdx.x & 31, ty = threadIdx.x >> 5;   // 32 x 8
    int n0 = nt * 32, k0 = kt * 32;
    #pragma unroll
    for (int j = 0; j < 4; j++) {
        int k = k0 + ty + j * 8;
        t[ty + j * 8][tx] = src[(size_t)k * N + n0 + tx];
    }
    __syncthreads();
    #pragma unroll
    for (int j = 0; j < 4; j++) {
        int n = n0 + ty + j * 8;
        dst[(size_t)n * K + k0 + tx] = (__bf16)(t[tx][ty + j * 8] * scale);
    }
}

__global__ void prep_bias_qkv(const float* __restrict__ bq, const float* __restrict__ bk,
                              const float* __restrict__ bv, float* __restrict__ outb)
{
    int i = blockIdx.x * 256 + threadIdx.x;   // 0..2303
    if (i >= 3 * DD) return;
    if (i < DD)            outb[i] = bq[i] * 0.125f;
    else if (i < 2 * DD)   outb[i] = bk[i - DD];
    else                   outb[i] = bv[i - 2 * DD];
}

// ---- GEMM: C[M,N] = act(A[M,K] @ Bt[N,K]^T + bias) ------------------------
// A, Bt bf16 (k-major both). 128x128 tile, 4 waves, 16x16x32 MFMA.
#define LDT 40
template<int ACT, int OUTBF>
__global__ __launch_bounds__(256) void gemm_bt(const __bf16* __restrict__ A,
                                               const __bf16* __restrict__ Bt,
                                               const float* __restrict__ bias,
                                               void* __restrict__ Cout,
                                               int M, int N, int K)
{
    __shared__ __bf16 As[128 * LDT];
    __shared__ __bf16 Bs[128 * LDT];
    const int tid  = threadIdx.x;
    const int lane = tid & 63, w = tid >> 6;
    const int wrow = w >> 1, wcol = w & 1;
    const int quad = lane >> 4, lr = lane & 15;
    const size_t m0 = (size_t)blockIdx.y * 128, n0 = (size_t)blockIdx.x * 128;

    f32x4 acc[4][4] = {};

    const int r0 = tid >> 2, sg = tid & 3;        // chunk 0: rows 0..63
    const int r1 = r0 + 64;                       // chunk 1: rows 64..127
    const __bf16* Abase = A  + m0 * K;
    const __bf16* Bbase = Bt + n0 * K;

    for (int k0 = 0; k0 < K; k0 += 32) {
        __syncthreads();
        uint4 va0 = *(const uint4*)(Abase + (size_t)r0 * K + k0 + sg * 8);
        uint4 va1 = *(const uint4*)(Abase + (size_t)r1 * K + k0 + sg * 8);
        uint4 vb0 = *(const uint4*)(Bbase + (size_t)r0 * K + k0 + sg * 8);
        uint4 vb1 = *(const uint4*)(Bbase + (size_t)r1 * K + k0 + sg * 8);
        *(uint4*)&As[r0 * LDT + sg * 8] = va0;
        *(uint4*)&As[r1 * LDT + sg * 8] = va1;
        *(uint4*)&Bs[r0 * LDT + sg * 8] = vb0;
        *(uint4*)&Bs[r1 * LDT + sg * 8] = vb1;
        __syncthreads();

        bf16x8 af[4], bfv[4];
        #pragma unroll
        for (int mt = 0; mt < 4; mt++)
            af[mt] = *(const bf16x8*)&As[(wrow * 64 + mt * 16 + lr) * LDT + quad * 8];
        #pragma unroll
        for (int nt = 0; nt < 4; nt++)
            bfv[nt] = *(const bf16x8*)&Bs[(wcol * 64 + nt * 16 + lr) * LDT + quad * 8];
        #pragma unroll
        for (int mt = 0; mt < 4; mt++)
            #pragma unroll
            for (int nt = 0; nt < 4; nt++)
                acc[mt][nt] = __builtin_amdgcn_mfma_f32_16x16x32_bf16(af[mt], bfv[nt], acc[mt][nt], 0, 0, 0);
    }

    #pragma unroll
    for (int nt = 0; nt < 4; nt++) {
        size_t col = n0 + wcol * 64 + nt * 16 + lr;
        float bvv = bias[col];
        #pragma unroll
        for (int mt = 0; mt < 4; mt++) {
            int rowb = wrow * 64 + mt * 16 + quad * 4;
            #pragma unroll
            for (int r = 0; r < 4; r++) {
                float v = acc[mt][nt][r] + bvv;
                if (ACT == 1) v = 0.5f * v * (1.0f + erff(v * 0.70710678118654752f));
                size_t off = (m0 + rowb + r) * (size_t)N + col;
                if (OUTBF) ((__bf16*)Cout)[off] = (__bf16)v;
                else       ((float*)Cout)[off]  = v;
            }
        }
    }
}

// ---- MFMA band attention ---------------------------------------------------
// Block: one (b, h, group of 4 query-chunks of 32). 4 waves, one chunk each.
// Q,K fragments loaded direct from global (k-major in qkv rows); V staged
// transposed+zero-filled in LDS; P round-trips via wave-private LDS.
#define VTS 200   // V^T row stride (bf16 elems): 192 keys + 8 pad (16B-aligned rows)
#define PS  104   // P row stride: 96 + 8 pad (16B-aligned rows)

__global__ __launch_bounds__(256) void band_attn_mfma(const __bf16* __restrict__ qkv,
                                                      __bf16* __restrict__ attn)
{
    __shared__ __bf16 VT[64 * VTS];        // 25.6 KB
    __shared__ __bf16 Pb[4][32 * PS];      // 26.6 KB
    const int tid = threadIdx.x;
    const int cb = blockIdx.x & 31;            // chunk-group (4 chunks each)
    const int hh = (blockIdx.x >> 5) % HH;
    const int b  = blockIdx.x / (32 * HH);
    const int c0 = cb * 4;
    const int key0 = c0 * WW - WW;             // global key index of VT col 0

    // stage V^T: 192 keys x 64 dims, zero-filled outside [0,S)
    for (int e = tid; e < 192 * 16; e += 256) {
        int key = e >> 4, dq = (e & 15) << 2;
        int kp = key0 + key;
        bf16x4 v = {(__bf16)0.f, (__bf16)0.f, (__bf16)0.f, (__bf16)0.f};
        if (kp >= 0 && kp < SS)
            v = *(const bf16x4*)(qkv + ((size_t)(b * SS + kp)) * (3 * DD) + 2 * DD + hh * DH + dq);
        VT[(dq + 0) * VTS + key] = v[0];
        VT[(dq + 1) * VTS + key] = v[1];
        VT[(dq + 2) * VTS + key] = v[2];
        VT[(dq + 3) * VTS + key] = v[3];
    }
    __syncthreads();

    const int w = tid >> 6, lane = tid & 63;
    const int quad = lane >> 4, lr = lane & 15;
    const int c = c0 + w;                      // this wave's 32-query chunk
    const size_t rowb = (size_t)(b * SS + c * WW);

    // Q fragments: A[m=lr][k=quad*8+j], m-tiles x k-tiles = 2x2
    bf16x8 aq[2][2];
    #pragma unroll
    for (int mt = 0; mt < 2; mt++)
        #pragma unroll
        for (int kt = 0; kt < 2; kt++)
            aq[mt][kt] = *(const bf16x8*)(qkv + (rowb + mt * 16 + lr) * (3 * DD)
                                          + hh * DH + kt * 32 + quad * 8);

    // scores S[32 x 96] = Q @ K^T  (K rows direct from global, clamped; masked below)
    f32x4 sc[2][6] = {};
    #pragma unroll
    for (int nt = 0; nt < 6; nt++) {
        int kp = c * WW - WW + nt * 16 + lr;
        int kpc = min(max(kp, 0), SS - 1);
        const __bf16* kr = qkv + ((size_t)(b * SS + kpc)) * (3 * DD) + DD + hh * DH + quad * 8;
        bf16x8 b0 = *(const bf16x8*)kr;
        bf16x8 b1 = *(const bf16x8*)(kr + 32);
        #pragma unroll
        for (int mt = 0; mt < 2; mt++) {
            sc[mt][nt] = __builtin_amdgcn_mfma_f32_16x16x32_bf16(aq[mt][0], b0, sc[mt][nt], 0, 0, 0);
            sc[mt][nt] = __builtin_amdgcn_mfma_f32_16x16x32_bf16(aq[mt][1], b1, sc[mt][nt], 0, 0, 0);
        }
    }

    // mask + softmax (C layout: row = mt*16 + quad*4 + r, col = nt*16 + lr) + P->LDS
    #pragma unroll
    for (int mt = 0; mt < 2; mt++) {
        #pragma unroll
        for (int r = 0; r < 4; r++) {
            int q = mt * 16 + quad * 4 + r;
            float m = -3.0e38f;
            #pragma unroll
            for (int nt = 0; nt < 6; nt++) {
                int col = nt * 16 + lr;
                int kg = c * WW - WW + col;
                bool ok = (col >= q) && (col <= q + 64) && (kg >= 0) && (kg < SS);
                float s = ok ? sc[mt][nt][r] : -3.0e38f;
                sc[mt][nt][r] = s;
                m = fmaxf(m, s);
            }
            m = fmaxf(m, __shfl_xor(m, 1));
            m = fmaxf(m, __shfl_xor(m, 2));
            m = fmaxf(m, __shfl_xor(m, 4));
            m = fmaxf(m, __shfl_xor(m, 8));
            float sum = 0.f;
            #pragma unroll
            for (int nt = 0; nt < 6; nt++) {
                float e = __expf(sc[mt][nt][r] - m);
                sc[mt][nt][r] = e;
                sum += e;
            }
            sum += __shfl_xor(sum, 1);
            sum += __shfl_xor(sum, 2);
            sum += __shfl_xor(sum, 4);
            sum += __shfl_xor(sum, 8);
            float inv = 1.f / sum;
            #pragma unroll
            for (int nt = 0; nt < 6; nt++)
                Pb[w][q * PS + nt * 16 + lr] = (__bf16)(sc[mt][nt][r] * inv);
        }
    }
    __syncthreads();   // uniform; orders P writes before A-fragment reads

    // PV: out[32 x 64] = P[32 x 96] @ V[96 x 64]
    f32x4 acc[2][4] = {};
    #pragma unroll
    for (int kt = 0; kt < 3; kt++) {
        bf16x8 ap0 = *(const bf16x8*)&Pb[w][(0 * 16 + lr) * PS + kt * 32 + quad * 8];
        bf16x8 ap1 = *(const bf16x8*)&Pb[w][(1 * 16 + lr) * PS + kt * 32 + quad * 8];
        #pragma unroll
        for (int nt = 0; nt < 4; nt++) {
            bf16x8 bv = *(const bf16x8*)&VT[(nt * 16 + lr) * VTS + w * WW + kt * 32 + quad * 8];
            acc[0][nt] = __builtin_amdgcn_mfma_f32_16x16x32_bf16(ap0, bv, acc[0][nt], 0, 0, 0);
            acc[1][nt] = __builtin_amdgcn_mfma_f32_16x16x32_bf16(ap1, bv, acc[1][nt], 0, 0, 0);
        }
    }

    #pragma unroll
    for (int mt = 0; mt < 2; mt++)
        #pragma unroll
        for (int nt = 0; nt < 4; nt++)
            #pragma unroll
            for (int r = 0; r < 4; r++) {
                int q = mt * 16 + quad * 4 + r;
                attn[(rowb + q) * DD + hh * DH + nt * 16 + lr] = (__bf16)acc[mt][nt][r];
            }
}

// ---- fused residual + layernorm: h = LN(h + tmp); hb = bf16(h) ------------
__global__ __launch_bounds__(256) void res_ln(float* __restrict__ h, const float* __restrict__ tmp,
                                              const float* __restrict__ gam, const float* __restrict__ bet,
                                              __bf16* __restrict__ hb)
{
    const int row = blockIdx.x, tid = threadIdx.x;
    const size_t base = (size_t)row * DD;
    float x[3]; float s = 0.f, q = 0.f;
    #pragma unroll
    for (int j = 0; j < 3; j++) {
        int d = tid + j * 256;
        float v = h[base + d] + tmp[base + d];
        x[j] = v; s += v; q += v * v;
    }
    __shared__ float red[8];
    int lane = tid & 63, w = tid >> 6;
    #pragma unroll
    for (int off = 32; off; off >>= 1) { s += __shfl_xor(s, off); q += __shfl_xor(q, off); }
    if (lane == 0) { red[w] = s; red[4 + w] = q; }
    __syncthreads();
    float S = red[0] + red[1] + red[2] + red[3];
    float Q = red[4] + red[5] + red[6] + red[7];
    float mean = S * (1.f / DD);
    float var  = fmaxf(Q * (1.f / DD) - mean * mean, 0.f);
    float rinv = rsqrtf(var + 1e-12f);
    #pragma unroll
    for (int j = 0; j < 3; j++) {
        int d = tid + j * 256;
        float y = (x[j] - mean) * rinv * gam[d] + bet[d];
        h[base + d] = y; hb[base + d] = (__bf16)y;
    }
}

// ---- embedding + layernorm ------------------------------------------------
__global__ __launch_bounds__(256) void embed_ln(const int* __restrict__ ids, const float* __restrict__ emb,
                                                const float* __restrict__ pos, const float* __restrict__ tok,
                                                const float* __restrict__ gam, const float* __restrict__ bet,
                                                float* __restrict__ h, __bf16* __restrict__ hb)
{
    const int row = blockIdx.x, tid = threadIdx.x;
    const int srow = row & (SS - 1);
    const int id = ids[row];
    const size_t base = (size_t)row * DD;
    float x[3]; float s = 0.f, q = 0.f;
    #pragma unroll
    for (int j = 0; j < 3; j++) {
        int d = tid + j * 256;
        float v = emb[(size_t)id * DD + d] + pos[(size_t)(srow + 1) * DD + d] + tok[d];
        x[j] = v; s += v; q += v * v;
    }
    __shared__ float red[8];
    int lane = tid & 63, w = tid >> 6;
    #pragma unroll
    for (int off = 32; off; off >>= 1) { s += __shfl_xor(s, off); q += __shfl_xor(q, off); }
    if (lane == 0) { red[w] = s; red[4 + w] = q; }
    __syncthreads();
    float S = red[0] + red[1] + red[2] + red[3];
    float Q = red[4] + red[5] + red[6] + red[7];
    float mean = S * (1.f / DD);
    float var  = fmaxf(Q * (1.f / DD) - mean * mean, 0.f);
    float rinv = rsqrtf(var + 1e-12f);
    #pragma unroll
    for (int j = 0; j < 3; j++) {
        int d = tid + j * 256;
        float y = (x[j] - mean) * rinv * gam[d] + bet[d];
        h[base + d] = y; hb[base + d] = (__bf16)y;
    }
}

// ---- final mean over S + tiny FC ------------------------------------------
__global__ void zero_kernel(float* __restrict__ p, int n)
{
    int i = blockIdx.x * 256 + threadIdx.x;
    if (i < n) p[i] = 0.f;
}

__global__ __launch_bounds__(256) void mean_kernel(const float* __restrict__ h, float* __restrict__ meanb)
{
    // grid: B * 32 * 3
    int blk = blockIdx.x;
    int b = blk / 96, rem = blk % 96;
    int sc = rem / 3, dg = rem % 3;
    int d = dg * 256 + threadIdx.x;
    float acc = 0.f;
    size_t base = ((size_t)b * SS + sc * 128) * DD + d;
    for (int s = 0; s < 128; s++) acc += h[base + (size_t)s * DD];
    atomicAdd(&meanb[b * DD + d], acc * (1.f / SS));
}

__global__ void fc_kernel(const float* __restrict__ meanb, const float* __restrict__ fw,
                          const float* __restrict__ fb, float* __restrict__ out)
{
    int b = blockIdx.x >> 4, n = blockIdx.x & 15;
    int lane = threadIdx.x;
    float acc = 0.f;
    #pragma unroll
    for (int j = 0; j < 12; j++) {
        int d = lane + j * 64;
        acc += meanb[b * DD + d] * fw[(size_t)d * NC + n];
    }
    #pragma unroll
    for (int off = 32; off; off >>= 1) acc += __shfl_xor(acc, off);
    if (lane == 0) out[b * NC + n] = acc + fb[n];
}

// ---- host -----------------------------------------------------------------
extern "C" void kernel_launch(void* const* d_in, const int* in_sizes, int n_in,
                              void* d_out, int out_size, void* d_ws, size_t ws_size,
                              hipStream_t stream)
{
    const int*   x    = (const int*)d_in[0];
    const float* emb  = (const float*)d_in[1];
    const float* pos  = (const float*)d_in[2];
    const float* tok  = (const float*)d_in[3];
    const float* elns = (const float*)d_in[4];
    const float* elnb = (const float*)d_in[5];
    const float* Wq   = (const float*)d_in[6];
    const float* bq   = (const float*)d_in[7];
    const float* Wk   = (const float*)d_in[8];
    const float* bk   = (const float*)d_in[9];
    const float* Wv   = (const float*)d_in[10];
    const float* bv   = (const float*)d_in[11];
    const float* Wo   = (const float*)d_in[12];
    const float* bo   = (const float*)d_in[13];
    const float* ln1s = (const float*)d_in[14];
    const float* ln1b = (const float*)d_in[15];
    const float* W1   = (const float*)d_in[16];
    const float* b1   = (const float*)d_in[17];
    const float* W2   = (const float*)d_in[18];
    const float* b2   = (const float*)d_in[19];
    const float* ln2s = (const float*)d_in[20];
    const float* ln2b = (const float*)d_in[21];
    const float* fcw  = (const float*)d_in[22];
    const float* fcb  = (const float*)d_in[23];
    float* out = (float*)d_out;

    char* wsp = (char*)d_ws;
    size_t off = 0;
    auto take = [&](size_t bytes) -> char* {
        char* p = wsp + off;
        off += (bytes + 255) & ~(size_t)255;
        return p;
    };
    float*  h    = (float*) take((size_t)MM * DD * 4);
    float*  tmp  = (float*) take((size_t)MM * DD * 4);
    __bf16* hb   = (__bf16*)take((size_t)MM * DD * 2);
    __bf16* qkv  = (__bf16*)take((size_t)MM * DFF * 2);  // union: qkv [M,2304] / ffh [M,3072]
    __bf16* ffh  = qkv;
    __bf16* attn = (__bf16*)take((size_t)MM * DD * 2);
    __bf16* wbt  = (__bf16*)take((size_t)DD * DFF * 2);  // per-GEMM transposed weights
    float*  bqkv = (float*) take(3 * DD * 4);
    float*  mnb  = (float*) take(BB * DD * 4);
    (void)ws_size; (void)in_sizes; (void)n_in; (void)out_size;

    embed_ln<<<MM, 256, 0, stream>>>(x, emb, pos, tok, elns, elnb, h, hb);

    for (int l = 0; l < LL; l++) {
        const float* Wq_l = Wq + (size_t)l * DD * DD;
        const float* Wk_l = Wk + (size_t)l * DD * DD;
        const float* Wv_l = Wv + (size_t)l * DD * DD;
        const float* Wo_l = Wo + (size_t)l * DD * DD;
        const float* W1_l = W1 + (size_t)l * DD * DFF;
        const float* W2_l = W2 + (size_t)l * DFF * DD;

        // QKV projection (scale folded into Wq/bq)
        transpose_w<<<dim3(24, 24), 256, 0, stream>>>(Wq_l, wbt,                 DD, DD, 0.125f);
        transpose_w<<<dim3(24, 24), 256, 0, stream>>>(Wk_l, wbt + DD * DD,       DD, DD, 1.f);
        transpose_w<<<dim3(24, 24), 256, 0, stream>>>(Wv_l, wbt + 2 * DD * DD,   DD, DD, 1.f);
        prep_bias_qkv<<<9, 256, 0, stream>>>(bq + l * DD, bk + l * DD, bv + l * DD, bqkv);
        gemm_bt<0, 1><<<dim3(18, 64), 256, 0, stream>>>(hb, wbt, bqkv, qkv, MM, 3 * DD, DD);

        band_attn_mfma<<<BB * HH * (CC / 4), 256, 0, stream>>>(qkv, attn);

        // output projection + LN1
        transpose_w<<<dim3(24, 24), 256, 0, stream>>>(Wo_l, wbt, DD, DD, 1.f);
        gemm_bt<0, 0><<<dim3(6, 64), 256, 0, stream>>>(attn, wbt, bo + l * DD, tmp, MM, DD, DD);
        res_ln<<<MM, 256, 0, stream>>>(h, tmp, ln1s + l * DD, ln1b + l * DD, hb);

        // FFN
        transpose_w<<<dim3(96, 24), 256, 0, stream>>>(W1_l, wbt, DD, DFF, 1.f);
        gemm_bt<1, 1><<<dim3(24, 64), 256, 0, stream>>>(hb, wbt, b1 + l * DFF, ffh, MM, DFF, DD);
        transpose_w<<<dim3(24, 96), 256, 0, stream>>>(W2_l, wbt, DFF, DD, 1.f);
        gemm_bt<0, 0><<<dim3(6, 64), 256, 0, stream>>>(ffh, wbt, b2 + l * DD, tmp, MM, DD, DFF);
        res_ln<<<MM, 256, 0, stream>>>(h, tmp, ln2s + l * DD, ln2b + l * DD, hb);
    }

    zero_kernel<<<6, 256, 0, stream>>>(mnb, BB * DD);
    mean_kernel<<<BB * 32 * 3, 256, 0, stream>>>(h, mnb);
    fc_kernel<<<BB * NC, 64, 0, stream>>>(mnb, fcw, fcb, out);
}

// Round 3
// 3893.801 us; speedup vs baseline: 1.4721x; 1.0266x over previous
//
#include <hip/hip_runtime.h>
#include <math.h>

// ---- constants -------------------------------------------------------------
#define BB 2
#define SS 4096
#define DD 768
#define HH 12
#define DH 64
#define LL 12
#define DFF 3072
#define NC 16
#define WW 32
#define CC (SS/WW)          // 128
#define MM (BB*SS)          // 8192

typedef __bf16 bf16x8 __attribute__((ext_vector_type(8)));
typedef __bf16 bf16x4 __attribute__((ext_vector_type(4)));
typedef float  f32x4  __attribute__((ext_vector_type(4)));

typedef const __attribute__((address_space(1))) void* gas_t;
typedef __attribute__((address_space(3))) void* las_t;

// ---- weight transpose + bf16 convert: dst[n][k] = bf16(src[k][n]*scale) ----
__global__ __launch_bounds__(256) void transpose_w(const float* __restrict__ src,
                                                   __bf16* __restrict__ dst,
                                                   int K, int N, float scale)
{
    __shared__ float t[32][33];
    int nt = blockIdx.x, kt = blockIdx.y;
    int tx = threadIdx.x & 31, ty = threadIdx.x >> 5;   // 32 x 8
    int n0 = nt * 32, k0 = kt * 32;
    #pragma unroll
    for (int j = 0; j < 4; j++) {
        int k = k0 + ty + j * 8;
        t[ty + j * 8][tx] = src[(size_t)k * N + n0 + tx];
    }
    __syncthreads();
    #pragma unroll
    for (int j = 0; j < 4; j++) {
        int n = n0 + ty + j * 8;
        dst[(size_t)n * K + k0 + tx] = (__bf16)(t[tx][ty + j * 8] * scale);
    }
}

__global__ void prep_bias_qkv(const float* __restrict__ bq, const float* __restrict__ bk,
                              const float* __restrict__ bv, float* __restrict__ outb)
{
    int i = blockIdx.x * 256 + threadIdx.x;   // 0..2303
    if (i >= 3 * DD) return;
    if (i < DD)            outb[i] = bq[i] * 0.125f;
    else if (i < 2 * DD)   outb[i] = bk[i - DD];
    else                   outb[i] = bv[i - 2 * DD];
}

// ---- GEMM: C[M,N] = act(A[M,K] @ Bt[N,K]^T + bias) ------------------------
// A, Bt bf16 (k-major both). 128x128 tile, 4 waves, 16x16x32 MFMA.
// m97-style staging: global_load_lds width=16 into unpadded [128][32] tiles.
template<int ACT, int OUTBF>
__global__ __launch_bounds__(256) void gemm_bt(const __bf16* __restrict__ A,
                                               const __bf16* __restrict__ Bt,
                                               const float* __restrict__ bias,
                                               void* __restrict__ Cout,
                                               int M, int N, int K)
{
    __shared__ __bf16 As[128 * 32];
    __shared__ __bf16 Bs[128 * 32];
    const int tid  = threadIdx.x;
    const int lane = tid & 63, w = tid >> 6;
    const int wrow = w >> 1, wcol = w & 1;
    const int quad = lane >> 4, lr = lane & 15;
    const size_t m0 = (size_t)blockIdx.y * 128, n0 = (size_t)blockIdx.x * 128;

    f32x4 acc[4][4] = {};

    // staging: wave w covers tile rows [w*32, w*32+32); two 16-row DMA issues
    // lane -> row w*32 + j*16 + (lane>>2), bf16 col (lane&3)*8  (16B per lane)
    const int srow = w * 32 + (lane >> 2);
    const int kcol = (lane & 3) * 8;
    const __bf16* Ag0 = A  + (m0 + srow) * (size_t)K + kcol;
    const __bf16* Ag1 = Ag0 + 16 * (size_t)K;
    const __bf16* Bg0 = Bt + (n0 + srow) * (size_t)K + kcol;
    const __bf16* Bg1 = Bg0 + 16 * (size_t)K;
    __bf16* As0 = &As[(w * 32) * 32];          // wave-uniform LDS bases
    __bf16* As1 = &As[(w * 32 + 16) * 32];
    __bf16* Bs0 = &Bs[(w * 32) * 32];
    __bf16* Bs1 = &Bs[(w * 32 + 16) * 32];

    for (int k0 = 0; k0 < K; k0 += 32) {
        __syncthreads();
        __builtin_amdgcn_global_load_lds((gas_t)(Ag0 + k0), (las_t)As0, 16, 0, 0);
        __builtin_amdgcn_global_load_lds((gas_t)(Ag1 + k0), (las_t)As1, 16, 0, 0);
        __builtin_amdgcn_global_load_lds((gas_t)(Bg0 + k0), (las_t)Bs0, 16, 0, 0);
        __builtin_amdgcn_global_load_lds((gas_t)(Bg1 + k0), (las_t)Bs1, 16, 0, 0);
        __syncthreads();

        bf16x8 af[4], bfv[4];
        #pragma unroll
        for (int mt = 0; mt < 4; mt++)
            af[mt] = *(const bf16x8*)&As[(wrow * 64 + mt * 16 + lr) * 32 + quad * 8];
        #pragma unroll
        for (int nt = 0; nt < 4; nt++)
            bfv[nt] = *(const bf16x8*)&Bs[(wcol * 64 + nt * 16 + lr) * 32 + quad * 8];
        #pragma unroll
        for (int mt = 0; mt < 4; mt++)
            #pragma unroll
            for (int nt = 0; nt < 4; nt++)
                acc[mt][nt] = __builtin_amdgcn_mfma_f32_16x16x32_bf16(af[mt], bfv[nt], acc[mt][nt], 0, 0, 0);
    }

    #pragma unroll
    for (int nt = 0; nt < 4; nt++) {
        size_t col = n0 + wcol * 64 + nt * 16 + lr;
        float bvv = bias[col];
        #pragma unroll
        for (int mt = 0; mt < 4; mt++) {
            int rowb = wrow * 64 + mt * 16 + quad * 4;
            #pragma unroll
            for (int r = 0; r < 4; r++) {
                float v = acc[mt][nt][r] + bvv;
                if (ACT == 1) v = 0.5f * v * (1.0f + erff(v * 0.70710678118654752f));
                size_t off = (m0 + rowb + r) * (size_t)N + col;
                if (OUTBF) ((__bf16*)Cout)[off] = (__bf16)v;
                else       ((float*)Cout)[off]  = v;
            }
        }
    }
}

// ---- MFMA band attention ---------------------------------------------------
// Block: one (b, h, group of 4 query-chunks of 32). 4 waves, one chunk each.
#define VTS 200   // V^T row stride (bf16 elems): 192 keys + 8 pad
#define PS  104   // P row stride: 96 + 8 pad

__global__ __launch_bounds__(256) void band_attn_mfma(const __bf16* __restrict__ qkv,
                                                      __bf16* __restrict__ attn)
{
    __shared__ __bf16 VT[64 * VTS];        // 25.6 KB
    __shared__ __bf16 Pb[4][32 * PS];      // 26.6 KB
    const int tid = threadIdx.x;
    const int cb = blockIdx.x & 31;            // chunk-group (4 chunks each)
    const int hh = (blockIdx.x >> 5) % HH;
    const int b  = blockIdx.x / (32 * HH);
    const int c0 = cb * 4;
    const int key0 = c0 * WW - WW;             // global key index of VT col 0

    // stage V^T: 192 keys x 64 dims, zero-filled outside [0,S)
    for (int e = tid; e < 192 * 16; e += 256) {
        int key = e >> 4, dq = (e & 15) << 2;
        int kp = key0 + key;
        bf16x4 v = {(__bf16)0.f, (__bf16)0.f, (__bf16)0.f, (__bf16)0.f};
        if (kp >= 0 && kp < SS)
            v = *(const bf16x4*)(qkv + ((size_t)(b * SS + kp)) * (3 * DD) + 2 * DD + hh * DH + dq);
        VT[(dq + 0) * VTS + key] = v[0];
        VT[(dq + 1) * VTS + key] = v[1];
        VT[(dq + 2) * VTS + key] = v[2];
        VT[(dq + 3) * VTS + key] = v[3];
    }
    __syncthreads();

    const int w = tid >> 6, lane = tid & 63;
    const int quad = lane >> 4, lr = lane & 15;
    const int c = c0 + w;                      // this wave's 32-query chunk
    const size_t rowb = (size_t)(b * SS + c * WW);

    // Q fragments: A[m=lr][k=quad*8+j], m-tiles x k-tiles = 2x2
    bf16x8 aq[2][2];
    #pragma unroll
    for (int mt = 0; mt < 2; mt++)
        #pragma unroll
        for (int kt = 0; kt < 2; kt++)
            aq[mt][kt] = *(const bf16x8*)(qkv + (rowb + mt * 16 + lr) * (3 * DD)
                                          + hh * DH + kt * 32 + quad * 8);

    // scores S[32 x 96] = Q @ K^T  (K rows direct from global, clamped; masked below)
    f32x4 sc[2][6] = {};
    #pragma unroll
    for (int nt = 0; nt < 6; nt++) {
        int kp = c * WW - WW + nt * 16 + lr;
        int kpc = min(max(kp, 0), SS - 1);
        const __bf16* kr = qkv + ((size_t)(b * SS + kpc)) * (3 * DD) + DD + hh * DH + quad * 8;
        bf16x8 b0 = *(const bf16x8*)kr;
        bf16x8 b1 = *(const bf16x8*)(kr + 32);
        #pragma unroll
        for (int mt = 0; mt < 2; mt++) {
            sc[mt][nt] = __builtin_amdgcn_mfma_f32_16x16x32_bf16(aq[mt][0], b0, sc[mt][nt], 0, 0, 0);
            sc[mt][nt] = __builtin_amdgcn_mfma_f32_16x16x32_bf16(aq[mt][1], b1, sc[mt][nt], 0, 0, 0);
        }
    }

    // mask + softmax (C layout: row = mt*16 + quad*4 + r, col = nt*16 + lr) + P->LDS
    #pragma unroll
    for (int mt = 0; mt < 2; mt++) {
        #pragma unroll
        for (int r = 0; r < 4; r++) {
            int q = mt * 16 + quad * 4 + r;
            float m = -3.0e38f;
            #pragma unroll
            for (int nt = 0; nt < 6; nt++) {
                int col = nt * 16 + lr;
                int kg = c * WW - WW + col;
                bool ok = (col >= q) && (col <= q + 64) && (kg >= 0) && (kg < SS);
                float s = ok ? sc[mt][nt][r] : -3.0e38f;
                sc[mt][nt][r] = s;
                m = fmaxf(m, s);
            }
            m = fmaxf(m, __shfl_xor(m, 1));
            m = fmaxf(m, __shfl_xor(m, 2));
            m = fmaxf(m, __shfl_xor(m, 4));
            m = fmaxf(m, __shfl_xor(m, 8));
            float sum = 0.f;
            #pragma unroll
            for (int nt = 0; nt < 6; nt++) {
                float e = __expf(sc[mt][nt][r] - m);
                sc[mt][nt][r] = e;
                sum += e;
            }
            sum += __shfl_xor(sum, 1);
            sum += __shfl_xor(sum, 2);
            sum += __shfl_xor(sum, 4);
            sum += __shfl_xor(sum, 8);
            float inv = 1.f / sum;
            #pragma unroll
            for (int nt = 0; nt < 6; nt++)
                Pb[w][q * PS + nt * 16 + lr] = (__bf16)(sc[mt][nt][r] * inv);
        }
    }
    __syncthreads();   // uniform; orders P writes before A-fragment reads

    // PV: out[32 x 64] = P[32 x 96] @ V[96 x 64]
    f32x4 acc[2][4] = {};
    #pragma unroll
    for (int kt = 0; kt < 3; kt++) {
        bf16x8 ap0 = *(const bf16x8*)&Pb[w][(0 * 16 + lr) * PS + kt * 32 + quad * 8];
        bf16x8 ap1 = *(const bf16x8*)&Pb[w][(1 * 16 + lr) * PS + kt * 32 + quad * 8];
        #pragma unroll
        for (int nt = 0; nt < 4; nt++) {
            bf16x8 bv = *(const bf16x8*)&VT[(nt * 16 + lr) * VTS + w * WW + kt * 32 + quad * 8];
            acc[0][nt] = __builtin_amdgcn_mfma_f32_16x16x32_bf16(ap0, bv, acc[0][nt], 0, 0, 0);
            acc[1][nt] = __builtin_amdgcn_mfma_f32_16x16x32_bf16(ap1, bv, acc[1][nt], 0, 0, 0);
        }
    }

    #pragma unroll
    for (int mt = 0; mt < 2; mt++)
        #pragma unroll
        for (int nt = 0; nt < 4; nt++)
            #pragma unroll
            for (int r = 0; r < 4; r++) {
                int q = mt * 16 + quad * 4 + r;
                attn[(rowb + q) * DD + hh * DH + nt * 16 + lr] = (__bf16)acc[mt][nt][r];
            }
}

// ---- fused residual + layernorm: h = LN(h + tmp); hb = bf16(h) ------------
__global__ __launch_bounds__(256) void res_ln(float* __restrict__ h, const float* __restrict__ tmp,
                                              const float* __restrict__ gam, const float* __restrict__ bet,
                                              __bf16* __restrict__ hb)
{
    const int row = blockIdx.x, tid = threadIdx.x;
    const size_t base = (size_t)row * DD;
    float x[3]; float s = 0.f, q = 0.f;
    #pragma unroll
    for (int j = 0; j < 3; j++) {
        int d = tid + j * 256;
        float v = h[base + d] + tmp[base + d];
        x[j] = v; s += v; q += v * v;
    }
    __shared__ float red[8];
    int lane = tid & 63, w = tid >> 6;
    #pragma unroll
    for (int off = 32; off; off >>= 1) { s += __shfl_xor(s, off); q += __shfl_xor(q, off); }
    if (lane == 0) { red[w] = s; red[4 + w] = q; }
    __syncthreads();
    float S = red[0] + red[1] + red[2] + red[3];
    float Q = red[4] + red[5] + red[6] + red[7];
    float mean = S * (1.f / DD);
    float var  = fmaxf(Q * (1.f / DD) - mean * mean, 0.f);
    float rinv = rsqrtf(var + 1e-12f);
    #pragma unroll
    for (int j = 0; j < 3; j++) {
        int d = tid + j * 256;
        float y = (x[j] - mean) * rinv * gam[d] + bet[d];
        h[base + d] = y; hb[base + d] = (__bf16)y;
    }
}

// ---- embedding + layernorm ------------------------------------------------
__global__ __launch_bounds__(256) void embed_ln(const int* __restrict__ ids, const float* __restrict__ emb,
                                                const float* __restrict__ pos, const float* __restrict__ tok,
                                                const float* __restrict__ gam, const float* __restrict__ bet,
                                                float* __restrict__ h, __bf16* __restrict__ hb)
{
    const int row = blockIdx.x, tid = threadIdx.x;
    const int srow = row & (SS - 1);
    const int id = ids[row];
    const size_t base = (size_t)row * DD;
    float x[3]; float s = 0.f, q = 0.f;
    #pragma unroll
    for (int j = 0; j < 3; j++) {
        int d = tid + j * 256;
        float v = emb[(size_t)id * DD + d] + pos[(size_t)(srow + 1) * DD + d] + tok[d];
        x[j] = v; s += v; q += v * v;
    }
    __shared__ float red[8];
    int lane = tid & 63, w = tid >> 6;
    #pragma unroll
    for (int off = 32; off; off >>= 1) { s += __shfl_xor(s, off); q += __shfl_xor(q, off); }
    if (lane == 0) { red[w] = s; red[4 + w] = q; }
    __syncthreads();
    float S = red[0] + red[1] + red[2] + red[3];
    float Q = red[4] + red[5] + red[6] + red[7];
    float mean = S * (1.f / DD);
    float var  = fmaxf(Q * (1.f / DD) - mean * mean, 0.f);
    float rinv = rsqrtf(var + 1e-12f);
    #pragma unroll
    for (int j = 0; j < 3; j++) {
        int d = tid + j * 256;
        float y = (x[j] - mean) * rinv * gam[d] + bet[d];
        h[base + d] = y; hb[base + d] = (__bf16)y;
    }
}

// ---- final mean over S + tiny FC ------------------------------------------
__global__ void zero_kernel(float* __restrict__ p, int n)
{
    int i = blockIdx.x * 256 + threadIdx.x;
    if (i < n) p[i] = 0.f;
}

__global__ __launch_bounds__(256) void mean_kernel(const float* __restrict__ h, float* __restrict__ meanb)
{
    // grid: B * 32 * 3
    int blk = blockIdx.x;
    int b = blk / 96, rem = blk % 96;
    int sc = rem / 3, dg = rem % 3;
    int d = dg * 256 + threadIdx.x;
    float acc = 0.f;
    size_t base = ((size_t)b * SS + sc * 128) * DD + d;
    for (int s = 0; s < 128; s++) acc += h[base + (size_t)s * DD];
    atomicAdd(&meanb[b * DD + d], acc * (1.f / SS));
}

__global__ void fc_kernel(const float* __restrict__ meanb, const float* __restrict__ fw,
                          const float* __restrict__ fb, float* __restrict__ out)
{
    int b = blockIdx.x >> 4, n = blockIdx.x & 15;
    int lane = threadIdx.x;
    float acc = 0.f;
    #pragma unroll
    for (int j = 0; j < 12; j++) {
        int d = lane + j * 64;
        acc += meanb[b * DD + d] * fw[(size_t)d * NC + n];
    }
    #pragma unroll
    for (int off = 32; off; off >>= 1) acc += __shfl_xor(acc, off);
    if (lane == 0) out[b * NC + n] = acc + fb[n];
}

// ---- host -----------------------------------------------------------------
extern "C" void kernel_launch(void* const* d_in, const int* in_sizes, int n_in,
                              void* d_out, int out_size, void* d_ws, size_t ws_size,
                              hipStream_t stream)
{
    const int*   x    = (const int*)d_in[0];
    const float* emb  = (const float*)d_in[1];
    const float* pos  = (const float*)d_in[2];
    const float* tok  = (const float*)d_in[3];
    const float* elns = (const float*)d_in[4];
    const float* elnb = (const float*)d_in[5];
    const float* Wq   = (const float*)d_in[6];
    const float* bq   = (const float*)d_in[7];
    const float* Wk   = (const float*)d_in[8];
    const float* bk   = (const float*)d_in[9];
    const float* Wv   = (const float*)d_in[10];
    const float* bv   = (const float*)d_in[11];
    const float* Wo   = (const float*)d_in[12];
    const float* bo   = (const float*)d_in[13];
    const float* ln1s = (const float*)d_in[14];
    const float* ln1b = (const float*)d_in[15];
    const float* W1   = (const float*)d_in[16];
    const float* b1   = (const float*)d_in[17];
    const float* W2   = (const float*)d_in[18];
    const float* b2   = (const float*)d_in[19];
    const float* ln2s = (const float*)d_in[20];
    const float* ln2b = (const float*)d_in[21];
    const float* fcw  = (const float*)d_in[22];
    const float* fcb  = (const float*)d_in[23];
    float* out = (float*)d_out;

    char* wsp = (char*)d_ws;
    size_t off = 0;
    auto take = [&](size_t bytes) -> char* {
        char* p = wsp + off;
        off += (bytes + 255) & ~(size_t)255;
        return p;
    };
    float*  h    = (float*) take((size_t)MM * DD * 4);
    float*  tmp  = (float*) take((size_t)MM * DD * 4);
    __bf16* hb   = (__bf16*)take((size_t)MM * DD * 2);
    __bf16* qkv  = (__bf16*)take((size_t)MM * DFF * 2);  // union: qkv [M,2304] / ffh [M,3072]
    __bf16* ffh  = qkv;
    __bf16* attn = (__bf16*)take((size_t)MM * DD * 2);
    __bf16* wbt  = (__bf16*)take((size_t)DD * DFF * 2);  // per-GEMM transposed weights
    float*  bqkv = (float*) take(3 * DD * 4);
    float*  mnb  = (float*) take(BB * DD * 4);
    (void)ws_size; (void)in_sizes; (void)n_in; (void)out_size;

    embed_ln<<<MM, 256, 0, stream>>>(x, emb, pos, tok, elns, elnb, h, hb);

    for (int l = 0; l < LL; l++) {
        const float* Wq_l = Wq + (size_t)l * DD * DD;
        const float* Wk_l = Wk + (size_t)l * DD * DD;
        const float* Wv_l = Wv + (size_t)l * DD * DD;
        const float* Wo_l = Wo + (size_t)l * DD * DD;
        const float* W1_l = W1 + (size_t)l * DD * DFF;
        const float* W2_l = W2 + (size_t)l * DFF * DD;

        // QKV projection (scale folded into Wq/bq)
        transpose_w<<<dim3(24, 24), 256, 0, stream>>>(Wq_l, wbt,                 DD, DD, 0.125f);
        transpose_w<<<dim3(24, 24), 256, 0, stream>>>(Wk_l, wbt + DD * DD,       DD, DD, 1.f);
        transpose_w<<<dim3(24, 24), 256, 0, stream>>>(Wv_l, wbt + 2 * DD * DD,   DD, DD, 1.f);
        prep_bias_qkv<<<9, 256, 0, stream>>>(bq + l * DD, bk + l * DD, bv + l * DD, bqkv);
        gemm_bt<0, 1><<<dim3(18, 64), 256, 0, stream>>>(hb, wbt, bqkv, qkv, MM, 3 * DD, DD);

        band_attn_mfma<<<BB * HH * (CC / 4), 256, 0, stream>>>(qkv, attn);

        // output projection + LN1
        transpose_w<<<dim3(24, 24), 256, 0, stream>>>(Wo_l, wbt, DD, DD, 1.f);
        gemm_bt<0, 0><<<dim3(6, 64), 256, 0, stream>>>(attn, wbt, bo + l * DD, tmp, MM, DD, DD);
        res_ln<<<MM, 256, 0, stream>>>(h, tmp, ln1s + l * DD, ln1b + l * DD, hb);

        // FFN
        transpose_w<<<dim3(96, 24), 256, 0, stream>>>(W1_l, wbt, DD, DFF, 1.f);
        gemm_bt<1, 1><<<dim3(24, 64), 256, 0, stream>>>(hb, wbt, b1 + l * DFF, ffh, MM, DFF, DD);
        transpose_w<<<dim3(24, 96), 256, 0, stream>>>(W2_l, wbt, DFF, DD, 1.f);
        gemm_bt<0, 0><<<dim3(6, 64), 256, 0, stream>>>(ffh, wbt, b2 + l * DD, tmp, MM, DD, DFF);
        res_ln<<<MM, 256, 0, stream>>>(h, tmp, ln2s + l * DD, ln2b + l * DD, hb);
    }

    zero_kernel<<<6, 256, 0, stream>>>(mnb, BB * DD);
    mean_kernel<<<BB * 32 * 3, 256, 0, stream>>>(h, mnb);
    fc_kernel<<<BB * NC, 64, 0, stream>>>(mnb, fcw, fcb, out);
}